// Round 1
// baseline (303.612 us; speedup 1.0000x reference)
//
#include <hip/hip_runtime.h>

// Aggregator: out[n, :] = mean over s of features[neighbor_idx[n, s], :]
// features: [200000, 128] fp32, neighbor_idx: [100000, 25] int32 (JAX default
// x64-disabled => int64 request silently becomes int32), out: [100000, 128] fp32.

#define N_NODES     100000
#define NUM_SAMPLES 25
#define DIM         128
#define NODES_PER_BLOCK 4

__global__ __launch_bounds__(256) void
Aggregator_45286135169721_kernel(const float* __restrict__ features,
                                 const int* __restrict__ neighbor_idx,
                                 float* __restrict__ out) {
    const int wave = threadIdx.x >> 6;        // 0..3, one node per wave
    const int lane = threadIdx.x & 63;        // 64 lanes
    const int node = blockIdx.x * NODES_PER_BLOCK + wave;
    if (node >= N_NODES) return;

    const int* __restrict__ row_idx = neighbor_idx + (size_t)node * NUM_SAMPLES;
    const int col = lane * 2;                 // each lane owns 2 columns

    float s0 = 0.0f, s1 = 0.0f;
    // Fully unrolled: all 25 index loads + 25 float2 gathers can be in flight.
    #pragma unroll
    for (int s = 0; s < NUM_SAMPLES; ++s) {
        const int r = row_idx[s];             // wave-uniform load (broadcast)
        const float2 v =
            *reinterpret_cast<const float2*>(features + (size_t)r * DIM + col);
        s0 += v.x;
        s1 += v.y;
    }

    const float inv = 1.0f / (float)NUM_SAMPLES;
    float2 o;
    o.x = s0 * inv;
    o.y = s1 * inv;
    *reinterpret_cast<float2*>(out + (size_t)node * DIM + col) = o;
}

extern "C" void kernel_launch(void* const* d_in, const int* in_sizes, int n_in,
                              void* d_out, int out_size, void* d_ws, size_t ws_size,
                              hipStream_t stream) {
    const float* features     = (const float*)d_in[0];
    const int*   neighbor_idx = (const int*)d_in[1];
    float*       out          = (float*)d_out;

    const int blocks = (N_NODES + NODES_PER_BLOCK - 1) / NODES_PER_BLOCK; // 25000
    Aggregator_45286135169721_kernel<<<blocks, 256, 0, stream>>>(
        features, neighbor_idx, out);
}